// Round 1
// baseline (124.729 us; speedup 1.0000x reference)
//
#include <hip/hip_runtime.h>
#include <math.h>

namespace {
constexpr int KMAX  = 12;
constexpr int NSIDE = 2 * KMAX + 1;            // 25
constexpr int NK    = NSIDE * NSIDE * NSIDE;   // 15625
constexpr int NHALF = (NK - 1) / 2;            // 7812 (positive half-space)
constexpr float ALPHA_  = 0.34f;
constexpr float TWO_PI_ = 6.283185307179586f;
}

__global__ void init_ws(float* ws) { ws[0] = 0.0f; }

// One wave (64 lanes) per k-vector in the positive half-space.
__global__ __launch_bounds__(256) void ewald_half(
    const float* __restrict__ coords,
    const float* __restrict__ box,
    const float* __restrict__ q,
    int N, float* __restrict__ ws)
{
  const int wid  = (blockIdx.x * 256 + threadIdx.x) >> 6;
  const int lane = threadIdx.x & 63;
  if (wid >= NHALF) return;                       // wave-uniform exit
  const int f = wid + NHALF + 1;                  // full linear index 7813..15624
  const int h = f / (NSIDE * NSIDE) - KMAX;
  const int r = f % (NSIDE * NSIDE);
  const int k = r / NSIDE - KMAX;
  const int l = r % NSIDE - KMAX;

  // G = inv(box); krev = h*G[:,0] + k*G[:,1] + l*G[:,2]  (phase in revolutions)
  const float b00 = box[0], b01 = box[1], b02 = box[2];
  const float b10 = box[3], b11 = box[4], b12 = box[5];
  const float b20 = box[6], b21 = box[7], b22 = box[8];
  const float C00 =  (b11 * b22 - b12 * b21);
  const float C01 = -(b10 * b22 - b12 * b20);
  const float C02 =  (b10 * b21 - b11 * b20);
  const float C10 = -(b01 * b22 - b02 * b21);
  const float C11 =  (b00 * b22 - b02 * b20);
  const float C12 = -(b00 * b21 - b01 * b20);
  const float C20 =  (b01 * b12 - b02 * b11);
  const float C21 = -(b00 * b12 - b02 * b10);
  const float C22 =  (b00 * b11 - b01 * b10);
  const float det    = b00 * C00 + b01 * C01 + b02 * C02;
  const float invdet = 1.0f / det;
  const float hf = (float)h, kf = (float)k, lf = (float)l;
  const float kx = (hf * C00 + kf * C10 + lf * C20) * invdet;
  const float ky = (hf * C01 + kf * C11 + lf * C21) * invdet;
  const float kz = (hf * C02 + kf * C12 + lf * C22) * invdet;
  const float k2 = TWO_PI_ * TWO_PI_ * (kx * kx + ky * ky + kz * kz);
  const float inv4a2 = 1.0f / (4.0f * ALPHA_ * ALPHA_);
  const float fac = __expf(-k2 * inv4a2) / k2;

  float Sre = 0.0f, Sim = 0.0f;
  for (int i = lane; i < N; i += 64) {
    const float x  = coords[3 * i + 0];
    const float y  = coords[3 * i + 1];
    const float z  = coords[3 * i + 2];
    const float qi = q[i];
    float t = fmaf(x, kx, fmaf(y, ky, z * kz));   // revolutions
    t = t - floorf(t);                             // range-reduce for v_sin/v_cos
    float s, c;
    asm("v_sin_f32 %0, %1" : "=v"(s) : "v"(t));
    asm("v_cos_f32 %0, %1" : "=v"(c) : "v"(t));
    Sre = fmaf(qi, c, Sre);
    Sim = fmaf(qi, s, Sim);
  }
#pragma unroll
  for (int off = 32; off > 0; off >>= 1) {
    Sre += __shfl_down(Sre, off);
    Sim += __shfl_down(Sim, off);
  }
  if (lane == 0) {
    atomicAdd(ws, fac * (Sre * Sre + Sim * Sim));
  }
}

__global__ void finalize(const float* __restrict__ ws,
                         const float* __restrict__ box,
                         float* __restrict__ out)
{
  const float b00 = box[0], b01 = box[1], b02 = box[2];
  const float b10 = box[3], b11 = box[4], b12 = box[5];
  const float b20 = box[6], b21 = box[7], b22 = box[8];
  const float det = b00 * (b11 * b22 - b12 * b21)
                  - b01 * (b10 * b22 - b12 * b20)
                  + b02 * (b10 * b21 - b11 * b20);
  const float vol = fabsf(det);
  // E = (2*pi/V) * sum_full = (2*pi/V) * 2 * sum_half = (4*pi/V) * ws[0]
  out[0] = (4.0f * 3.14159265358979323846f / vol) * ws[0];
}

extern "C" void kernel_launch(void* const* d_in, const int* in_sizes, int n_in,
                              void* d_out, int out_size, void* d_ws, size_t ws_size,
                              hipStream_t stream) {
  const float* coords = (const float*)d_in[0];
  const float* box    = (const float*)d_in[1];
  const float* q      = (const float*)d_in[2];
  float* out = (float*)d_out;
  float* ws  = (float*)d_ws;
  const int N = in_sizes[2];  // q element count (coords is 3N)

  hipLaunchKernelGGL(init_ws, dim3(1), dim3(1), 0, stream, ws);
  const int blocks = (NHALF + 3) / 4;  // 4 waves (k-vectors) per 256-thread block
  hipLaunchKernelGGL(ewald_half, dim3(blocks), dim3(256), 0, stream,
                     coords, box, q, N, ws);
  hipLaunchKernelGGL(finalize, dim3(1), dim3(1), 0, stream, ws, box, out);
}

// Round 2
// 37.167 us; speedup vs baseline: 3.3559x; 3.3559x over previous
//
#include <hip/hip_runtime.h>
#include <math.h>

namespace {
constexpr int   KMAX   = 12;
constexpr int   NSIDE  = 2 * KMAX + 1;          // 25
constexpr int   NK     = NSIDE * NSIDE * NSIDE; // 15625
constexpr int   NHALF  = (NK - 1) / 2;          // 7812 positive half-space k-vecs
constexpr int   KPW    = 2;                     // k-vectors per wave
constexpr int   NWAVE  = NHALF / KPW;           // 3906 waves
constexpr int   NMAX   = 4096;                  // particle capacity (LDS tile)
constexpr float ALPHA_  = 0.34f;
constexpr float TWO_PI_ = 6.283185307179586f;
}

// ---- cofactor helpers (3x3 inverse via adjugate) ----
__device__ __forceinline__ void cofactors(const float* __restrict__ box,
                                          float C[3][3], float* det) {
  const float b00 = box[0], b01 = box[1], b02 = box[2];
  const float b10 = box[3], b11 = box[4], b12 = box[5];
  const float b20 = box[6], b21 = box[7], b22 = box[8];
  C[0][0] =  (b11 * b22 - b12 * b21);
  C[0][1] = -(b10 * b22 - b12 * b20);
  C[0][2] =  (b10 * b21 - b11 * b20);
  C[1][0] = -(b01 * b22 - b02 * b21);
  C[1][1] =  (b00 * b22 - b02 * b20);
  C[1][2] = -(b00 * b21 - b01 * b20);
  C[2][0] =  (b01 * b12 - b02 * b11);
  C[2][1] = -(b00 * b12 - b02 * b10);
  C[2][2] =  (b00 * b11 - b01 * b10);
  *det = b00 * C[0][0] + b01 * C[0][1] + b02 * C[0][2];
}

// Pack per-particle fractional coords + charge: f = (r . inv(box), q).
// Phase(h,k,l) for particle i is then h*a + k*b + l*c  (in revolutions).
__global__ __launch_bounds__(256) void make_frac(
    const float* __restrict__ coords, const float* __restrict__ box,
    const float* __restrict__ q, int N, float4* __restrict__ frac)
{
  const int i = blockIdx.x * 256 + threadIdx.x;
  if (i >= N) return;
  float C[3][3], det;
  cofactors(box, C, &det);
  const float invdet = 1.0f / det;
  const float x = coords[3 * i + 0];
  const float y = coords[3 * i + 1];
  const float z = coords[3 * i + 2];
  float4 f;
  f.x = (x * C[0][0] + y * C[0][1] + z * C[0][2]) * invdet; // a
  f.y = (x * C[1][0] + y * C[1][1] + z * C[1][2]) * invdet; // b
  f.z = (x * C[2][0] + y * C[2][1] + z * C[2][2]) * invdet; // c
  f.w = q[i];
  frac[i] = f;
}

// One wave handles KPW consecutive half-space k-vectors; particles staged in LDS.
__global__ __launch_bounds__(256) void ewald2(
    const float4* __restrict__ frac, const float* __restrict__ box,
    int N, float* __restrict__ partial)
{
  __shared__ float4 sf[NMAX];
  const int NL = (N < NMAX) ? N : NMAX;
  for (int idx = threadIdx.x; idx < NL; idx += 256) sf[idx] = frac[idx];
  __syncthreads();

  const int wid  = (blockIdx.x * 256 + threadIdx.x) >> 6;
  const int lane = threadIdx.x & 63;
  if (wid >= NWAVE) return;

  float C[3][3], det;
  cofactors(box, C, &det);
  const float invdet = 1.0f / det;
  const float inv4a2 = 1.0f / (4.0f * ALPHA_ * ALPHA_);

  float hf[KPW], kf_[KPW], lf[KPW], fac[KPW];
#pragma unroll
  for (int u = 0; u < KPW; ++u) {
    const int f = wid * KPW + u + NHALF + 1;  // linear index in full 25^3 grid
    const int h = f / (NSIDE * NSIDE) - KMAX;
    const int r = f % (NSIDE * NSIDE);
    const int k = r / NSIDE - KMAX;
    const int l = r % NSIDE - KMAX;
    hf[u] = (float)h; kf_[u] = (float)k; lf[u] = (float)l;
    // k-vector in "revolutions" units: kvec = inv(box) @ (h,k,l)
    const float kx = (hf[u] * C[0][0] + kf_[u] * C[1][0] + lf[u] * C[2][0]) * invdet;
    const float ky = (hf[u] * C[0][1] + kf_[u] * C[1][1] + lf[u] * C[2][1]) * invdet;
    const float kz = (hf[u] * C[0][2] + kf_[u] * C[1][2] + lf[u] * C[2][2]) * invdet;
    const float k2 = TWO_PI_ * TWO_PI_ * (kx * kx + ky * ky + kz * kz);
    fac[u] = __expf(-k2 * inv4a2) / k2;
  }

  float Sre[KPW], Sim[KPW];
#pragma unroll
  for (int u = 0; u < KPW; ++u) { Sre[u] = 0.0f; Sim[u] = 0.0f; }

#pragma unroll 4
  for (int i = lane; i < NL; i += 64) {
    const float4 p = sf[i];
#pragma unroll
    for (int u = 0; u < KPW; ++u) {
      float t = fmaf(p.x, hf[u], fmaf(p.y, kf_[u], p.z * lf[u]));  // revolutions
      t = t - floorf(t);
      float s, c;
      asm("v_sin_f32 %0, %1" : "=v"(s) : "v"(t));
      asm("v_cos_f32 %0, %1" : "=v"(c) : "v"(t));
      Sre[u] = fmaf(p.w, c, Sre[u]);
      Sim[u] = fmaf(p.w, s, Sim[u]);
    }
  }

#pragma unroll
  for (int off = 32; off > 0; off >>= 1) {
#pragma unroll
    for (int u = 0; u < KPW; ++u) {
      Sre[u] += __shfl_down(Sre[u], off);
      Sim[u] += __shfl_down(Sim[u], off);
    }
  }
  if (lane == 0) {
    float e = 0.0f;
#pragma unroll
    for (int u = 0; u < KPW; ++u)
      e = fmaf(fac[u], fmaf(Sre[u], Sre[u], Sim[u] * Sim[u]), e);
    partial[wid] = e;   // no atomics: deterministic per-wave partials
  }
}

// Single-block tree reduction of the 3906 per-wave partials; applies 4*pi/V.
__global__ __launch_bounds__(256) void finalize_reduce(
    const float* __restrict__ partial, const float* __restrict__ box,
    float* __restrict__ out)
{
  __shared__ float red[256];
  float acc = 0.0f;
  for (int i = threadIdx.x; i < NWAVE; i += 256) acc += partial[i];
  red[threadIdx.x] = acc;
  __syncthreads();
  for (int s = 128; s > 0; s >>= 1) {
    if (threadIdx.x < s) red[threadIdx.x] += red[threadIdx.x + s];
    __syncthreads();
  }
  if (threadIdx.x == 0) {
    float C[3][3], det;
    cofactors(box, C, &det);
    const float vol = fabsf(det);
    // E = (2*pi/V) * full_sum = (4*pi/V) * half_sum
    out[0] = (4.0f * 3.14159265358979323846f / vol) * red[0];
  }
}

extern "C" void kernel_launch(void* const* d_in, const int* in_sizes, int n_in,
                              void* d_out, int out_size, void* d_ws, size_t ws_size,
                              hipStream_t stream) {
  const float* coords = (const float*)d_in[0];
  const float* box    = (const float*)d_in[1];
  const float* q      = (const float*)d_in[2];
  float* out = (float*)d_out;
  const int N = in_sizes[2];

  // ws layout: [0, 64KB): float4 frac table; [64KB, +NWAVE*4): per-wave partials
  float4* frac    = (float4*)d_ws;
  float*  partial = (float*)((char*)d_ws + (size_t)NMAX * sizeof(float4));

  hipLaunchKernelGGL(make_frac, dim3((N + 255) / 256), dim3(256), 0, stream,
                     coords, box, q, N, frac);
  const int blocks = (NWAVE * 64 + 255) / 256;   // 4 waves per block
  hipLaunchKernelGGL(ewald2, dim3(blocks), dim3(256), 0, stream,
                     frac, box, N, partial);
  hipLaunchKernelGGL(finalize_reduce, dim3(1), dim3(256), 0, stream,
                     partial, box, out);
}

// Round 3
// 21.544 us; speedup vs baseline: 5.7896x; 1.7252x over previous
//
#include <hip/hip_runtime.h>
#include <math.h>

namespace {
constexpr int   KMAX   = 12;
constexpr int   NSIDE  = 2 * KMAX + 1;           // 25
constexpr int   NLINE  = 313;                    // half-space (h,k) lines
constexpr int   NGROUP = NLINE * 5;              // 1565 l-groups of 5
constexpr int   NKV    = NGROUP * 5;             // 7825 computed k-vecs (13 masked)
constexpr int   NSLICE = 8;                      // particle slices
constexpr int   SLICE_CAP = 512;                 // staged particles per chunk
constexpr int   S2_BLOCKS = (NKV + 255) / 256;   // 31
constexpr float ALPHA_  = 0.34f;
constexpr float TWO_PI_ = 6.283185307179586f;
}

__device__ __forceinline__ void cofactors(const float* __restrict__ box,
                                          float C[3][3], float* det) {
  const float b00 = box[0], b01 = box[1], b02 = box[2];
  const float b10 = box[3], b11 = box[4], b12 = box[5];
  const float b20 = box[6], b21 = box[7], b22 = box[8];
  C[0][0] =  (b11 * b22 - b12 * b21);
  C[0][1] = -(b10 * b22 - b12 * b20);
  C[0][2] =  (b10 * b21 - b11 * b20);
  C[1][0] = -(b01 * b22 - b02 * b21);
  C[1][1] =  (b00 * b22 - b02 * b20);
  C[1][2] = -(b00 * b21 - b01 * b20);
  C[2][0] =  (b01 * b12 - b02 * b11);
  C[2][1] = -(b00 * b12 - b02 * b10);
  C[2][2] =  (b00 * b11 - b01 * b10);
  *det = b00 * C[0][0] + b01 * C[0][1] + b02 * C[0][2];
}

// Half-space lines: L<300: h=1..12 x k=-12..12; L=300..311: h=0,k=1..12; L=312: h=k=0.
__device__ __forceinline__ void line_hk(int L, int* h, int* k) {
  if (L < 300)      { *h = L / 25 + 1; *k = L % 25 - 12; }
  else if (L < 312) { *h = 0;          *k = L - 299;     }
  else              { *h = 0;          *k = 0;           }
}

// One wave = one l-group (5 consecutive l of one (h,k) line) x one particle slice.
// Per particle: 2 sincos + 4 complex rotations cover all 5 k-vectors.
__global__ __launch_bounds__(256) void ewald_groups(
    const float* __restrict__ coords, const float* __restrict__ box,
    const float* __restrict__ q, int N, float* __restrict__ partial)
{
  __shared__ float4 sf[SLICE_CAP];

  float C[3][3], det;
  cofactors(box, C, &det);
  const float invdet = 1.0f / det;

  const int slice = blockIdx.y;
  const int sp    = (N + NSLICE - 1) / NSLICE;
  const int s_beg = slice * sp;
  const int s_end = min(s_beg + sp, N);

  const int lane = threadIdx.x & 63;
  const int g    = blockIdx.x * 4 + (threadIdx.x >> 6);
  const int gc   = (g < NGROUP) ? g : (NGROUP - 1);   // clamp for decode; store guarded

  int h, k; line_hk(gc / 5, &h, &k);
  const float hf  = (float)h;
  const float kf  = (float)k;
  const float l0f = (float)(-KMAX + 5 * (gc % 5));

  float Sre[5] = {0.f, 0.f, 0.f, 0.f, 0.f};
  float Sim[5] = {0.f, 0.f, 0.f, 0.f, 0.f};

  for (int cb = s_beg; cb < s_end; cb += SLICE_CAP) {
    const int cnt = min(SLICE_CAP, s_end - cb);
    __syncthreads();
    // Stage fractional coords + charge for this chunk (pad with q=0).
    for (int t = threadIdx.x; t < SLICE_CAP; t += 256) {
      float4 v = make_float4(0.f, 0.f, 0.f, 0.f);
      if (t < cnt) {
        const int gi = cb + t;
        const float x = coords[3 * gi + 0];
        const float y = coords[3 * gi + 1];
        const float z = coords[3 * gi + 2];
        v.x = (x * C[0][0] + y * C[0][1] + z * C[0][2]) * invdet;  // a
        v.y = (x * C[1][0] + y * C[1][1] + z * C[1][2]) * invdet;  // b
        float c = (x * C[2][0] + y * C[2][1] + z * C[2][2]) * invdet;
        v.z = c - floorf(c);                                       // c in [0,1)
        v.w = q[gi];
      }
      sf[t] = v;
    }
    __syncthreads();

    for (int i = lane; i < SLICE_CAP; i += 64) {
      const float4 p = sf[i];
      float t = fmaf(hf, p.x, fmaf(kf, p.y, l0f * p.z));  // phase(l0) in revolutions
      float tf;
      asm("v_fract_f32 %0, %1" : "=v"(tf) : "v"(t));
      float s0, c0, sr, cr;
      asm("v_sin_f32 %0, %1" : "=v"(s0) : "v"(tf));
      asm("v_cos_f32 %0, %1" : "=v"(c0) : "v"(tf));
      asm("v_sin_f32 %0, %1" : "=v"(sr) : "v"(p.z));      // rotator e^{i*2pi*c}
      asm("v_cos_f32 %0, %1" : "=v"(cr) : "v"(p.z));
      float Pre = p.w * c0, Pim = p.w * s0;               // q folded into phasor
      Sre[0] += Pre; Sim[0] += Pim;
#pragma unroll
      for (int u = 1; u < 5; ++u) {
        const float nre = fmaf(Pre, cr, -(Pim * sr));
        const float nim = fmaf(Pre, sr,  (Pim * cr));
        Pre = nre; Pim = nim;
        Sre[u] += Pre; Sim[u] += Pim;
      }
    }
  }

#pragma unroll
  for (int off = 32; off > 0; off >>= 1) {
#pragma unroll
    for (int u = 0; u < 5; ++u) {
      Sre[u] += __shfl_down(Sre[u], off);
      Sim[u] += __shfl_down(Sim[u], off);
    }
  }
  if (g < NGROUP && lane == 0) {
    float* dst = partial + (size_t)(g * NSLICE + slice) * 10;
#pragma unroll
    for (int u = 0; u < 5; ++u) {
      dst[2 * u + 0] = Sre[u];
      dst[2 * u + 1] = Sim[u];
    }
  }
}

// Sum slices, square, weight by fac; per-block partial sums (deterministic).
__global__ __launch_bounds__(256) void stage2(
    const float* __restrict__ partial, const float* __restrict__ box,
    float* __restrict__ bsum)
{
  __shared__ float red[256];
  const int idx = blockIdx.x * 256 + threadIdx.x;
  float e = 0.f;
  if (idx < NKV) {
    const int g = idx / 5, u = idx % 5;
    const int L = g / 5, sub = g % 5;
    int h, k; line_hk(L, &h, &k);
    const int l = -KMAX + 5 * sub + u;
    if (!(h == 0 && k == 0 && l <= 0)) {   // mask the 13 extra type-C entries
      float re = 0.f, im = 0.f;
      for (int s = 0; s < NSLICE; ++s) {
        const float* p = partial + (size_t)(g * NSLICE + s) * 10 + 2 * u;
        re += p[0]; im += p[1];
      }
      float C[3][3], det;
      cofactors(box, C, &det);
      const float invdet = 1.0f / det;
      const float hf = (float)h, kf = (float)k, lf = (float)l;
      const float kx = (hf * C[0][0] + kf * C[1][0] + lf * C[2][0]) * invdet;
      const float ky = (hf * C[0][1] + kf * C[1][1] + lf * C[2][1]) * invdet;
      const float kz = (hf * C[0][2] + kf * C[1][2] + lf * C[2][2]) * invdet;
      const float k2 = TWO_PI_ * TWO_PI_ * (kx * kx + ky * ky + kz * kz);
      const float fac = __expf(-k2 / (4.0f * ALPHA_ * ALPHA_)) / k2;
      e = fac * fmaf(re, re, im * im);
    }
  }
  red[threadIdx.x] = e;
  __syncthreads();
  for (int s = 128; s > 0; s >>= 1) {
    if (threadIdx.x < s) red[threadIdx.x] += red[threadIdx.x + s];
    __syncthreads();
  }
  if (threadIdx.x == 0) bsum[blockIdx.x] = red[0];
}

__global__ void finalize(const float* __restrict__ bsum,
                         const float* __restrict__ box,
                         float* __restrict__ out)
{
  if (threadIdx.x == 0) {
    float acc = 0.f;
    for (int i = 0; i < S2_BLOCKS; ++i) acc += bsum[i];
    float C[3][3], det;
    cofactors(box, C, &det);
    // E = (2*pi/V)*full_sum = (4*pi/V)*half_sum
    out[0] = (4.0f * 3.14159265358979323846f / fabsf(det)) * acc;
  }
}

extern "C" void kernel_launch(void* const* d_in, const int* in_sizes, int n_in,
                              void* d_out, int out_size, void* d_ws, size_t ws_size,
                              hipStream_t stream) {
  const float* coords = (const float*)d_in[0];
  const float* box    = (const float*)d_in[1];
  const float* q      = (const float*)d_in[2];
  float* out = (float*)d_out;
  const int N = in_sizes[2];

  // ws: [0, NGROUP*NSLICE*10*4 = 500,800 B) partial S; [512 KiB, +124 B) block sums
  float* partial = (float*)d_ws;
  float* bsum    = (float*)((char*)d_ws + (512 << 10));

  const dim3 grid((NGROUP + 3) / 4, NSLICE);
  hipLaunchKernelGGL(ewald_groups, grid, dim3(256), 0, stream,
                     coords, box, q, N, partial);
  hipLaunchKernelGGL(stage2, dim3(S2_BLOCKS), dim3(256), 0, stream,
                     partial, box, bsum);
  hipLaunchKernelGGL(finalize, dim3(1), dim3(64), 0, stream, bsum, box, out);
}